// Round 1
// baseline (21696.880 us; speedup 1.0000x reference)
//
#include <hip/hip_runtime.h>
#include <hip/hip_bf16.h>
#include <math.h>

#define SEQ   32
#define BATCH 1024
#define NN    19
#define HH    128
#define MROWS (BATCH*NN)   /* 19456 */

// ---------------------------------------------------------------------------
// Chebyshev build: one block per batch element. Builds
//   X[row, 0:F]   = x0 = concat(x_in (Fx), h (128) [* r])
//   X[row, F:2F]  = x1 = S @ x0
//   X[row, 2F:3F] = x2 = 2*S@x1 - x0
// rows = b*19+n, X row stride = 3F (== GEMM K).
// ---------------------------------------------------------------------------
__global__ __launch_bounds__(256) void cheb_kernel(
    const float* __restrict__ x_in, int Fx,      // (B*N, Fx) or nullptr => zeros
    const float* __restrict__ h,                 // (B*N, 128)
    const float* __restrict__ r,                 // (B*N, 256), cols 0..127 used, or nullptr
    const float* __restrict__ S,                 // (19,19)
    float* __restrict__ X, int F)                // (B*N, 3F)
{
    __shared__ float sS[NN*NN];
    __shared__ float sx0[NN*256];
    __shared__ float sx1[NN*256];
    const int b = blockIdx.x;
    const int tid = threadIdx.x;
    for (int i = tid; i < NN*NN; i += 256) sS[i] = S[i];
    const int total = NN * F;
    __syncthreads();

    for (int i = tid; i < total; i += 256) {
        int n = i / F, f = i - n*F;
        int row = b*NN + n;
        float v;
        if (f < Fx) {
            v = x_in ? x_in[(long)row*Fx + f] : 0.0f;
        } else {
            float hv = h[(long)row*HH + (f - Fx)];
            if (r) hv *= r[(long)row*256 + (f - Fx)];
            v = hv;
        }
        sx0[n*F + f] = v;
        X[(long)row*(3*F) + f] = v;
    }
    __syncthreads();

    for (int i = tid; i < total; i += 256) {
        int m = i / F, f = i - m*F;
        float acc = 0.f;
        #pragma unroll
        for (int n = 0; n < NN; ++n) acc += sS[m*NN + n] * sx0[n*F + f];
        sx1[m*F + f] = acc;
        X[(long)(b*NN + m)*(3*F) + F + f] = acc;
    }
    __syncthreads();

    for (int i = tid; i < total; i += 256) {
        int m = i / F, f = i - m*F;
        float acc = 0.f;
        #pragma unroll
        for (int n = 0; n < NN; ++n) acc += sS[m*NN + n] * sx1[n*F + f];
        X[(long)(b*NN + m)*(3*F) + 2*F + f] = 2.f*acc - sx0[m*F + f];
    }
}

// ---------------------------------------------------------------------------
// fp32 tiled GEMM: C(M,Nout) = act(A(M,K) @ W(K,Nout) + bias)
// BM=128, BN=64, BK=16; 256 threads, 8x4 micro-tile per thread.
// mode 0: ru[row*256+col] = sigmoid(v)                      (Nout=256)
// mode 1: c=tanh(v); u=ru[row*256+128+col];
//         h[row*128+col] = u*h + (1-u)*c   (in place)       (Nout=128)
// ---------------------------------------------------------------------------
#define BM 128
#define BN 64
#define BK 16

__global__ __launch_bounds__(256) void gemm_kernel(
    const float* __restrict__ A, int K,
    const float* __restrict__ W, int Nout,
    const float* __restrict__ bias,
    int mode,
    float* __restrict__ ru,
    float* __restrict__ hbuf)
{
    __shared__ float sA[BM][BK+1];
    __shared__ float sB[BK][BN+1];
    const int tid = threadIdx.x;
    const int rowBase = blockIdx.x * BM;
    const int colBase = blockIdx.y * BN;
    const int tr = tid >> 4;   // 0..15 -> rows tr*8..tr*8+7
    const int tc = tid & 15;   // 0..15 -> cols tc*4..tc*4+3

    float acc[8][4];
    #pragma unroll
    for (int i = 0; i < 8; ++i)
        #pragma unroll
        for (int j = 0; j < 4; ++j) acc[i][j] = 0.f;

    for (int k0 = 0; k0 < K; k0 += BK) {
        #pragma unroll
        for (int i = 0; i < 8; ++i) {            // A: 128x16 = 2048
            int idx = tid + i*256;
            int rr = idx >> 4, cc = idx & 15;
            int k = k0 + cc;
            sA[rr][cc] = (k < K) ? A[(long)(rowBase + rr)*K + k] : 0.f;
        }
        #pragma unroll
        for (int i = 0; i < 4; ++i) {            // B: 16x64 = 1024
            int idx = tid + i*256;
            int rr = idx >> 6, cc = idx & 63;
            int k = k0 + rr;
            sB[rr][cc] = (k < K) ? W[(long)k*Nout + colBase + cc] : 0.f;
        }
        __syncthreads();
        #pragma unroll
        for (int kk = 0; kk < BK; ++kk) {
            float a[8], bb[4];
            #pragma unroll
            for (int i = 0; i < 8; ++i) a[i] = sA[tr*8 + i][kk];
            #pragma unroll
            for (int j = 0; j < 4; ++j) bb[j] = sB[kk][tc*4 + j];
            #pragma unroll
            for (int i = 0; i < 8; ++i)
                #pragma unroll
                for (int j = 0; j < 4; ++j)
                    acc[i][j] = fmaf(a[i], bb[j], acc[i][j]);
        }
        __syncthreads();
    }

    #pragma unroll
    for (int i = 0; i < 8; ++i) {
        int row = rowBase + tr*8 + i;
        #pragma unroll
        for (int j = 0; j < 4; ++j) {
            int col = colBase + tc*4 + j;
            float v = acc[i][j] + bias[col];
            if (mode == 0) {
                ru[(long)row*256 + col] = 1.f / (1.f + __expf(-v));
            } else {
                float c = tanhf(v);
                float u = ru[(long)row*256 + 128 + col];
                float hold = hbuf[(long)row*HH + col];
                hbuf[(long)row*HH + col] = u*hold + (1.f - u)*c;
            }
        }
    }
}

// ---------------------------------------------------------------------------
// Projection: out[row] = dot(h[row,:], Wp) + bp. One wave per row.
// ---------------------------------------------------------------------------
__global__ __launch_bounds__(256) void proj_kernel(
    const float* __restrict__ h,    // (M,128)
    const float* __restrict__ Wp,   // (128,)
    const float* __restrict__ bp,   // (1,)
    float* __restrict__ out)        // (M,)
{
    const int wave = threadIdx.x >> 6;
    const int lane = threadIdx.x & 63;
    const int row  = blockIdx.x * 4 + wave;
    const float* hr = h + (long)row * HH;
    float s = hr[lane] * Wp[lane] + hr[64 + lane] * Wp[64 + lane];
    #pragma unroll
    for (int off = 32; off; off >>= 1) s += __shfl_down(s, off, 64);
    if (lane == 0) out[row] = s + bp[0];
}

// ---------------------------------------------------------------------------
extern "C" void kernel_launch(void* const* d_in, const int* in_sizes, int n_in,
                              void* d_out, int out_size, void* d_ws, size_t ws_size,
                              hipStream_t stream) {
    const float* ihs = (const float*)d_in[1];   // (2, B, N*H)
    const float* S   = (const float*)d_in[2];   // (19,19)
    const float* Wg0 = (const float*)d_in[3];   // (387,256)
    const float* bg0 = (const float*)d_in[4];
    const float* Wc0 = (const float*)d_in[5];   // (387,128)
    const float* bc0 = (const float*)d_in[6];
    const float* Wg1 = (const float*)d_in[7];   // (768,256)
    const float* bg1 = (const float*)d_in[8];
    const float* Wc1 = (const float*)d_in[9];   // (768,128)
    const float* bc1 = (const float*)d_in[10];
    const float* Wp  = (const float*)d_in[11];  // (128,1)
    const float* bp  = (const float*)d_in[12];  // (1,)
    float* out = (float*)d_out;                 // (32, 1024, 19)

    char* ws = (char*)d_ws;
    size_t off = 0;
    float* h0 = (float*)(ws + off); off += (size_t)MROWS*HH*4;   // 9.96 MB
    float* h1 = (float*)(ws + off); off += (size_t)MROWS*HH*4;   // 9.96 MB
    float* X  = (float*)(ws + off); off += (size_t)MROWS*768*4;  // 59.8 MB
    float* ru = (float*)(ws + off); off += (size_t)MROWS*256*4;  // 19.9 MB

    // init hidden state (layout (B,N,H) flat matches (B,N*H))
    hipMemcpyAsync(h0, ihs,                      (size_t)MROWS*HH*4,
                   hipMemcpyDeviceToDevice, stream);
    hipMemcpyAsync(h1, ihs + (size_t)MROWS*HH,   (size_t)MROWS*HH*4,
                   hipMemcpyDeviceToDevice, stream);

    for (int t = 0; t < SEQ; ++t) {
        const float* xprev = (t == 0) ? nullptr : (out + (size_t)(t-1)*MROWS);

        // ---- layer 0 (Fx=1, K=387) ----
        cheb_kernel<<<BATCH, 256, 0, stream>>>(xprev, 1, h0, nullptr, S, X, 129);
        gemm_kernel<<<dim3(152,4), 256, 0, stream>>>(X, 387, Wg0, 256, bg0, 0, ru, nullptr);
        cheb_kernel<<<BATCH, 256, 0, stream>>>(xprev, 1, h0, ru, S, X, 129);
        gemm_kernel<<<dim3(152,2), 256, 0, stream>>>(X, 387, Wc0, 128, bc0, 1, ru, h0);

        // ---- layer 1 (Fx=128, K=768), x_in = new h0 ----
        cheb_kernel<<<BATCH, 256, 0, stream>>>(h0, 128, h1, nullptr, S, X, 256);
        gemm_kernel<<<dim3(152,4), 256, 0, stream>>>(X, 768, Wg1, 256, bg1, 0, ru, nullptr);
        cheb_kernel<<<BATCH, 256, 0, stream>>>(h0, 128, h1, ru, S, X, 256);
        gemm_kernel<<<dim3(152,2), 256, 0, stream>>>(X, 768, Wc1, 128, bc1, 1, ru, h1);

        // ---- projection -> output t (also next step's input) ----
        proj_kernel<<<MROWS/4, 256, 0, stream>>>(h1, Wp, bp, out + (size_t)t*MROWS);
    }
}

// Round 2
// 7691.682 us; speedup vs baseline: 2.8208x; 2.8208x over previous
//
#include <hip/hip_runtime.h>
#include <hip/hip_bf16.h>
#include <math.h>

#define SEQ   32
#define BATCH 1024
#define NN    19
#define HH    128
#define MROWS (BATCH*NN)   /* 19456 */

typedef __attribute__((ext_vector_type(8))) short  bf16x8;
typedef __attribute__((ext_vector_type(4))) float  f32x4;

__device__ __forceinline__ unsigned short f2bf(float v) {
    __hip_bfloat16 b = __float2bfloat16(v);
    return *reinterpret_cast<unsigned short*>(&b);
}

__device__ __forceinline__ void llds16(const void* g, void* l) {
    __builtin_amdgcn_global_load_lds(
        (__attribute__((address_space(1))) void*)(void*)g,
        (__attribute__((address_space(3))) void*)l,
        16, 0, 0);
}

// ---------------------------------------------------------------------------
// Chebyshev build (bf16 out): one block per batch element. Builds
//   X[row, 0:F] = x0 = concat(x_in (Fx), h [* r]);  X[row,F:2F]=S@x0;
//   X[row,2F:3F]=2S@x1-x0;  X[row,3F:Kpad]=0.
// ---------------------------------------------------------------------------
__global__ __launch_bounds__(256) void cheb_kernel(
    const float* __restrict__ x_in, int Fx,
    const float* __restrict__ h,
    const float* __restrict__ r,          // (M,256) cols 0..127 used, or null
    const float* __restrict__ S,
    unsigned short* __restrict__ X, int F, int Kpad)
{
    __shared__ float sS[NN*NN];
    __shared__ float sx0[NN*256];
    __shared__ float sx1[NN*256];
    const int b = blockIdx.x;
    const int tid = threadIdx.x;
    for (int i = tid; i < NN*NN; i += 256) sS[i] = S[i];
    const int total = NN * F;
    __syncthreads();

    for (int i = tid; i < total; i += 256) {
        int n = i / F, f = i - n*F;
        int row = b*NN + n;
        float v;
        if (f < Fx) {
            v = x_in ? x_in[(size_t)row*Fx + f] : 0.0f;
        } else {
            float hv = h[(size_t)row*HH + (f - Fx)];
            if (r) hv *= r[(size_t)row*256 + (f - Fx)];
            v = hv;
        }
        sx0[n*F + f] = v;
        X[(size_t)row*Kpad + f] = f2bf(v);
    }
    // zero the K padding
    const int padc = Kpad - 3*F;
    for (int i = tid; i < NN*padc; i += 256) {
        int n = i / padc, c = i - n*padc;
        X[(size_t)(b*NN + n)*Kpad + 3*F + c] = 0;
    }
    __syncthreads();

    for (int i = tid; i < total; i += 256) {
        int m = i / F, f = i - m*F;
        float acc = 0.f;
        #pragma unroll
        for (int n = 0; n < NN; ++n) acc += sS[m*NN + n] * sx0[n*F + f];
        sx1[m*F + f] = acc;
        X[(size_t)(b*NN + m)*Kpad + F + f] = f2bf(acc);
    }
    __syncthreads();

    for (int i = tid; i < total; i += 256) {
        int m = i / F, f = i - m*F;
        float acc = 0.f;
        #pragma unroll
        for (int n = 0; n < NN; ++n) acc += sS[m*NN + n] * sx1[n*F + f];
        X[(size_t)(b*NN + m)*Kpad + 2*F + f] = f2bf(2.f*acc - sx0[m*F + f]);
    }
}

// ---------------------------------------------------------------------------
// Weight convert: WT[n, k] = bf16(W[k, n]), zero-padded to Kpad rows.
// ---------------------------------------------------------------------------
__global__ __launch_bounds__(256) void wconv_kernel(
    const float* __restrict__ W, unsigned short* __restrict__ WT,
    int K, int N, int Kpad)
{
    int idx = blockIdx.x * 256 + threadIdx.x;
    if (idx >= N * Kpad) return;
    int n = idx / Kpad, k = idx - n * Kpad;
    float v = (k < K) ? W[(size_t)k*N + n] : 0.f;
    WT[idx] = f2bf(v);
}

// ---------------------------------------------------------------------------
// bf16 MFMA GEMM. A: (M, Kpad) bf16 row-major; BT: (N, Kpad) bf16 row-major.
// 256 threads = 4 waves in 2x2; each wave computes (WMT*16) x (WNT*16).
// BM = 32*WMT, BN = 32*WNT. K staged in 32-wide slices via global_load_lds.
// mode 0: ru[row*256+col] = sigmoid(acc + bias[col])
// mode 1: c = tanh(acc+bias); u = ru[row*256+128+col];
//         hbuf[row*128+col] = u*h + (1-u)*c
// ---------------------------------------------------------------------------
template<int WMT, int WNT>
__global__ __launch_bounds__(256) void gemm_kernel(
    const unsigned short* __restrict__ A,
    const unsigned short* __restrict__ BT,
    int Kpad,
    const float* __restrict__ bias,
    int mode,
    float* __restrict__ ru,
    float* __restrict__ hbuf)
{
    constexpr int BM = 32*WMT, BN = 32*WNT;
    __shared__ unsigned short sA[BM*32];
    __shared__ unsigned short sB[BN*32];
    const int tid  = threadIdx.x;
    const int w    = tid >> 6, lane = tid & 63;
    const int wm   = w >> 1,   wn   = w & 1;
    const int rowBase = blockIdx.x * BM;
    const int colBase = blockIdx.y * BN;
    const int laneRow = lane >> 2;        // 0..15
    const int laneK   = (lane & 3) * 8;   // 0,8,16,24

    f32x4 acc[WMT][WNT];
    #pragma unroll
    for (int i = 0; i < WMT; ++i)
        #pragma unroll
        for (int j = 0; j < WNT; ++j) acc[i][j] = (f32x4)0.f;

    const int frow = lane & 15;           // fragment free-index
    const int fk   = (lane >> 4) * 8;     // fragment k-offset

    for (int k0 = 0; k0 < Kpad; k0 += 32) {
        #pragma unroll
        for (int cc = w; cc < BM/16; cc += 4) {
            const unsigned short* gp =
                A + (size_t)(rowBase + cc*16 + laneRow)*Kpad + k0 + laneK;
            llds16(gp, &sA[cc*512]);
        }
        #pragma unroll
        for (int cc = w; cc < BN/16; cc += 4) {
            const unsigned short* gp =
                BT + (size_t)(colBase + cc*16 + laneRow)*Kpad + k0 + laneK;
            llds16(gp, &sB[cc*512]);
        }
        __syncthreads();

        bf16x8 af[WMT], bfr[WNT];
        #pragma unroll
        for (int mt = 0; mt < WMT; ++mt)
            af[mt] = *(const bf16x8*)&sA[(wm*WMT*16 + mt*16 + frow)*32 + fk];
        #pragma unroll
        for (int nt = 0; nt < WNT; ++nt)
            bfr[nt] = *(const bf16x8*)&sB[(wn*WNT*16 + nt*16 + frow)*32 + fk];
        #pragma unroll
        for (int mt = 0; mt < WMT; ++mt)
            #pragma unroll
            for (int nt = 0; nt < WNT; ++nt)
                acc[mt][nt] = __builtin_amdgcn_mfma_f32_16x16x32_bf16(
                    af[mt], bfr[nt], acc[mt][nt], 0, 0, 0);
        __syncthreads();
    }

    const int tq = lane >> 4;
    #pragma unroll
    for (int mt = 0; mt < WMT; ++mt) {
        const int rbase = rowBase + wm*WMT*16 + mt*16 + tq*4;
        #pragma unroll
        for (int nt = 0; nt < WNT; ++nt) {
            const int col = colBase + wn*WNT*16 + nt*16 + (lane & 15);
            const float bv = bias[col];
            #pragma unroll
            for (int i = 0; i < 4; ++i) {
                const int row = rbase + i;
                float v = acc[mt][nt][i] + bv;
                if (mode == 0) {
                    ru[(size_t)row*256 + col] = 1.f / (1.f + __expf(-v));
                } else {
                    float c = tanhf(v);
                    float u = ru[(size_t)row*256 + 128 + col];
                    float hold = hbuf[(size_t)row*HH + col];
                    hbuf[(size_t)row*HH + col] = u*hold + (1.f - u)*c;
                }
            }
        }
    }
}

// ---------------------------------------------------------------------------
// Projection: out[row] = dot(h[row,:], Wp) + bp. One wave per row.
// ---------------------------------------------------------------------------
__global__ __launch_bounds__(256) void proj_kernel(
    const float* __restrict__ h,
    const float* __restrict__ Wp,
    const float* __restrict__ bp,
    float* __restrict__ out)
{
    const int wave = threadIdx.x >> 6;
    const int lane = threadIdx.x & 63;
    const int row  = blockIdx.x * 4 + wave;
    const float* hr = h + (size_t)row * HH;
    float s = hr[lane] * Wp[lane] + hr[64 + lane] * Wp[64 + lane];
    #pragma unroll
    for (int off = 32; off; off >>= 1) s += __shfl_down(s, off, 64);
    if (lane == 0) out[row] = s + bp[0];
}

// ---------------------------------------------------------------------------
extern "C" void kernel_launch(void* const* d_in, const int* in_sizes, int n_in,
                              void* d_out, int out_size, void* d_ws, size_t ws_size,
                              hipStream_t stream) {
    const float* ihs = (const float*)d_in[1];
    const float* S   = (const float*)d_in[2];
    const float* Wg0 = (const float*)d_in[3];   // (387,256)
    const float* bg0 = (const float*)d_in[4];
    const float* Wc0 = (const float*)d_in[5];   // (387,128)
    const float* bc0 = (const float*)d_in[6];
    const float* Wg1 = (const float*)d_in[7];   // (768,256)
    const float* bg1 = (const float*)d_in[8];
    const float* Wc1 = (const float*)d_in[9];   // (768,128)
    const float* bc1 = (const float*)d_in[10];
    const float* Wp  = (const float*)d_in[11];  // (128,1)
    const float* bp  = (const float*)d_in[12];
    float* out = (float*)d_out;                 // (32,1024,19)

    const int K0 = 416;   // 387 padded to 13*32
    const int K1 = 768;   // 3*256, 24*32

    char* ws = (char*)d_ws;
    size_t off = 0;
    float* h0 = (float*)(ws + off); off += (size_t)MROWS*HH*4;
    float* h1 = (float*)(ws + off); off += (size_t)MROWS*HH*4;
    unsigned short* X  = (unsigned short*)(ws + off); off += (size_t)MROWS*K1*2;
    float* ru = (float*)(ws + off); off += (size_t)MROWS*256*4;
    unsigned short* Tg0 = (unsigned short*)(ws + off); off += (size_t)256*K0*2;
    unsigned short* Tc0 = (unsigned short*)(ws + off); off += (size_t)128*K0*2;
    unsigned short* Tg1 = (unsigned short*)(ws + off); off += (size_t)256*K1*2;
    unsigned short* Tc1 = (unsigned short*)(ws + off); off += (size_t)128*K1*2;

    hipMemcpyAsync(h0, ihs,                    (size_t)MROWS*HH*4,
                   hipMemcpyDeviceToDevice, stream);
    hipMemcpyAsync(h1, ihs + (size_t)MROWS*HH, (size_t)MROWS*HH*4,
                   hipMemcpyDeviceToDevice, stream);

    wconv_kernel<<<(256*K0+255)/256, 256, 0, stream>>>(Wg0, Tg0, 387, 256, K0);
    wconv_kernel<<<(128*K0+255)/256, 256, 0, stream>>>(Wc0, Tc0, 387, 128, K0);
    wconv_kernel<<<(256*K1+255)/256, 256, 0, stream>>>(Wg1, Tg1, 768, 256, K1);
    wconv_kernel<<<(128*K1+255)/256, 256, 0, stream>>>(Wc1, Tc1, 768, 128, K1);

    for (int t = 0; t < SEQ; ++t) {
        const float* xprev = (t == 0) ? nullptr : (out + (size_t)(t-1)*MROWS);

        // ---- layer 0 (Fx=1, F=129, Kpad=416) ----
        cheb_kernel<<<BATCH, 256, 0, stream>>>(xprev, 1, h0, nullptr, S, X, 129, K0);
        gemm_kernel<4,4><<<dim3(MROWS/128, 2), 256, 0, stream>>>(
            X, Tg0, K0, bg0, 0, ru, nullptr);
        cheb_kernel<<<BATCH, 256, 0, stream>>>(xprev, 1, h0, ru, S, X, 129, K0);
        gemm_kernel<2,4><<<dim3(MROWS/64, 1), 256, 0, stream>>>(
            X, Tc0, K0, bc0, 1, ru, h0);

        // ---- layer 1 (Fx=128, F=256, Kpad=768) ----
        cheb_kernel<<<BATCH, 256, 0, stream>>>(h0, 128, h1, nullptr, S, X, 256, K1);
        gemm_kernel<4,4><<<dim3(MROWS/128, 2), 256, 0, stream>>>(
            X, Tg1, K1, bg1, 0, ru, nullptr);
        cheb_kernel<<<BATCH, 256, 0, stream>>>(h0, 128, h1, ru, S, X, 256, K1);
        gemm_kernel<2,4><<<dim3(MROWS/64, 1), 256, 0, stream>>>(
            X, Tc1, K1, bc1, 1, ru, h1);

        // ---- projection -> output t (= next step's input) ----
        proj_kernel<<<MROWS/4, 256, 0, stream>>>(h1, Wp, bp, out + (size_t)t*MROWS);
    }
}

// Round 4
// 5254.440 us; speedup vs baseline: 4.1292x; 1.4638x over previous
//
#include <hip/hip_runtime.h>
#include <hip/hip_bf16.h>
#include <math.h>

#define SEQ   32
#define BATCH 1024
#define NN    19
#define HH    128
#define NB    4            /* batch elements per block */
#define MR    (NB*NN)      /* 76 rows per block */
#define SAS   264          /* sA row stride (bf16): 528 B = 16B-aligned, 4-bank shift */
#define HS    132          /* h row stride (f32) */
#define UTS   72           /* Ut row stride (bf16): 144 B = 16B-aligned rows */

typedef __attribute__((ext_vector_type(8))) short  bf16x8;
typedef __attribute__((ext_vector_type(4))) float  f32x4;

__device__ __forceinline__ unsigned short f2bf(float v) {
    __hip_bfloat16 b = __float2bfloat16(v);
    return *reinterpret_cast<unsigned short*>(&b);
}
__device__ __forceinline__ float bf2f(unsigned short u) {
    unsigned int x = ((unsigned int)u) << 16;
    return __uint_as_float(x);
}

// ---------------------------------------------------------------------------
// Setup 1: weight reorder/transpose: BT[j][col][k] = bf16(W[j*F + k][col]),
// k zero-padded to KP. BT flat size = 3*O*KP.
// ---------------------------------------------------------------------------
__global__ __launch_bounds__(256) void wconv_kernel(
    const float* __restrict__ W, unsigned short* __restrict__ BT,
    int F, int O, int KP)
{
    int idx = blockIdx.x*256 + threadIdx.x;
    int total = 3*O*KP;
    if (idx >= total) return;
    int j   = idx / (O*KP);
    int r   = idx - j*(O*KP);
    int col = r / KP;
    int k   = r - col*KP;
    float v = (k < F) ? W[(size_t)(j*F + k)*O + col] : 0.f;
    BT[idx] = f2bf(v);
}

// ---------------------------------------------------------------------------
// Setup 2: T' (32 x 64) bf16: T'[m][j*19+n] = Tj[m,n]; T0=I, T1=S, T2=2S^2-I.
// Zero outside m<19, k<57.
// ---------------------------------------------------------------------------
__global__ __launch_bounds__(256) void tprime_kernel(
    const float* __restrict__ S, unsigned short* __restrict__ Tg)
{
    __shared__ float sS[NN*NN], sS2[NN*NN];
    int tid = threadIdx.x;
    for (int i = tid; i < NN*NN; i += 256) sS[i] = S[i];
    __syncthreads();
    for (int i = tid; i < NN*NN; i += 256) {
        int m = i/NN, n = i - m*NN;
        float a = 0.f;
        for (int k = 0; k < NN; ++k) a += sS[m*NN+k]*sS[k*NN+n];
        sS2[i] = a;
    }
    __syncthreads();
    for (int i = tid; i < 32*64; i += 256) {
        int m = i >> 6, k = i & 63;
        float v = 0.f;
        if (m < NN && k < 3*NN) {
            int j = k / NN, n = k - j*NN;
            float eye = (m == n) ? 1.f : 0.f;
            if (j == 0)      v = eye;
            else if (j == 1) v = sS[m*NN+n];
            else             v = 2.f*sS2[m*NN+n] - eye;
        }
        Tg[i] = f2bf(v);
    }
}

// ---------------------------------------------------------------------------
// Persistent block kernel: 256 blocks x 256 threads; block owns 4 batch
// elements for the whole 32-step rollout. All state in LDS.
// ---------------------------------------------------------------------------
#define LDS_BYTES 161296

template<int KS, int OC, bool GATE, int XW>
__device__ __forceinline__ void gconv_phase(
    const unsigned short* __restrict__ BT,   // (3, OC, KS*32) bf16
    const float* __restrict__ bias,          // (OC) fp32 global
    float* hL,                               // LDS h for this layer (MR x HS)
    unsigned short* sA,                      // LDS (80 x SAS)
    unsigned short* ub,                      // LDS u (MR x HS bf16)
    unsigned short* UtW,                     // this wave's Ut slab (32 x UTS)
    const bf16x8 (&tp)[2][2],
    int lane, int w)
{
    constexpr int NSG = OC/128;  // supergroups per wave (gate:2, cand:1)
    constexpr int KP  = KS*32;
    const int r16 = lane & 15, quad = lane >> 4;

    f32x4 acc[NSG][3][5][2];
    #pragma unroll
    for (int s = 0; s < NSG; ++s)
        #pragma unroll
        for (int j = 0; j < 3; ++j)
            #pragma unroll
            for (int mt = 0; mt < 5; ++mt)
                #pragma unroll
                for (int nt = 0; nt < 2; ++nt) acc[s][j][mt][nt] = (f32x4)0.f;

    // ---- main MFMA: U_j = x0 @ W_j for this wave's out-col chunks ----
    #pragma unroll
    for (int s = 0; s < NSG; ++s) {
        const int sgo = (w + 4*s) * 32;
        #pragma unroll
        for (int ks = 0; ks < KS; ++ks) {
            bf16x8 af[5];
            #pragma unroll
            for (int mt = 0; mt < 5; ++mt)
                af[mt] = *(const bf16x8*)&sA[(mt*16 + r16)*SAS + ks*32 + quad*8];
            #pragma unroll
            for (int j = 0; j < 3; ++j) {
                #pragma unroll
                for (int nt = 0; nt < 2; ++nt) {
                    const unsigned short* gp =
                        BT + (size_t)(j*OC + sgo + nt*16 + r16)*KP + ks*32 + quad*8;
                    bf16x8 bf = *(const bf16x8*)gp;
                    #pragma unroll
                    for (int mt = 0; mt < 5; ++mt)
                        acc[s][j][mt][nt] = __builtin_amdgcn_mfma_f32_16x16x32_bf16(
                            af[mt], bf, acc[s][j][mt][nt], 0, 0, 0);
                }
            }
        }
    }

    __syncthreads();   // all waves done reading sA before epilogue rewrites it

    // ---- per supergroup: scatter -> Ut, mix via MFMA with T', epilogue ----
    #pragma unroll
    for (int s = 0; s < NSG; ++s) {
        const int sgo = (w + 4*s)*32;
        const float bv0 = bias[sgo + r16];
        const float bv1 = bias[sgo + 16 + r16];
        for (int b = 0; b < NB; ++b) {
            // scatter this batch's rows of acc into Ut (k = j*19+n, k-contig rows)
            #pragma unroll
            for (int j = 0; j < 3; ++j)
                #pragma unroll
                for (int mt = 0; mt < 5; ++mt)
                    #pragma unroll
                    for (int reg = 0; reg < 4; ++reg) {
                        int gm = mt*16 + quad*4 + reg;
                        int n  = gm - b*NN;
                        if (n >= 0 && n < NN) {
                            #pragma unroll
                            for (int nt = 0; nt < 2; ++nt)
                                UtW[(nt*16 + r16)*UTS + j*NN + n] =
                                    f2bf(acc[s][j][mt][nt][reg]);
                        }
                    }
            // mixing: y = T' @ U   (M=32 pad of 19 nodes, K=64 pad of 57, N=32)
            f32x4 y[2][2];
            #pragma unroll
            for (int a = 0; a < 2; ++a)
                #pragma unroll
                for (int c = 0; c < 2; ++c) y[a][c] = (f32x4)0.f;
            #pragma unroll
            for (int kk = 0; kk < 2; ++kk)
                #pragma unroll
                for (int nt = 0; nt < 2; ++nt) {
                    bf16x8 uf = *(const bf16x8*)&UtW[(nt*16 + r16)*UTS + kk*32 + quad*8];
                    y[0][nt] = __builtin_amdgcn_mfma_f32_16x16x32_bf16(
                        tp[0][kk], uf, y[0][nt], 0, 0, 0);
                    y[1][nt] = __builtin_amdgcn_mfma_f32_16x16x32_bf16(
                        tp[1][kk], uf, y[1][nt], 0, 0, 0);
                }
            // epilogue
            #pragma unroll
            for (int mt2 = 0; mt2 < 2; ++mt2)
                #pragma unroll
                for (int nt = 0; nt < 2; ++nt)
                    #pragma unroll
                    for (int reg = 0; reg < 4; ++reg) {
                        int m = mt2*16 + quad*4 + reg;
                        if (m < NN) {
                            int o = sgo + nt*16 + r16;
                            float v = y[mt2][nt][reg] + (nt ? bv1 : bv0);
                            int row = b*NN + m;
                            if (GATE) {
                                float sg_ = 1.f/(1.f + __expf(-v));
                                if (o < HH)
                                    sA[row*SAS + XW + o] = f2bf(sg_ * hL[row*HS + o]);
                                else
                                    ub[row*HS + (o-HH)] = f2bf(sg_);
                            } else {
                                float c  = 2.f/(1.f + __expf(-2.f*v)) - 1.f;
                                float u  = bf2f(ub[row*HS + o]);
                                float ho = hL[row*HS + o];
                                hL[row*HS + o] = u*ho + (1.f - u)*c;
                            }
                        }
                    }
        }
    }
}

__global__ __launch_bounds__(256, 1) void dcgru_persistent(
    const float* __restrict__ ihs,
    const unsigned short* __restrict__ BTg0, const float* __restrict__ bg0,
    const unsigned short* __restrict__ BTc0, const float* __restrict__ bc0,
    const unsigned short* __restrict__ BTg1, const float* __restrict__ bg1,
    const unsigned short* __restrict__ BTc1, const float* __restrict__ bc1,
    const float* __restrict__ Wp, const float* __restrict__ bp,
    const unsigned short* __restrict__ Tg,
    float* __restrict__ out)
{
    extern __shared__ char smem[];
    float*          h0    = (float*)smem;                          // 76*132*4 = 40128
    float*          h1    = (float*)(smem + 40128);                // 40128
    unsigned short* sA    = (unsigned short*)(smem + 80256);       // 80*264*2 = 42240
    unsigned short* ub    = (unsigned short*)(smem + 122496);      // 76*132*2 = 20064
    unsigned short* Ut    = (unsigned short*)(smem + 142560);      // 4*32*72*2 = 18432
    float*          xprev = (float*)(smem + 160992);               // 76*4 = 304

    const int tid  = threadIdx.x;
    const int lane = tid & 63;
    const int w    = tid >> 6;
    const int bb   = blockIdx.x * NB;
    unsigned short* UtW = Ut + w*32*UTS;

    // init: hidden state global->LDS (19*128 == 2432 contiguous per batch elem)
    for (int i = tid; i < MR*HH; i += 256) {
        int row = i >> 7, f = i & 127;
        h0[row*HS + f] = ihs[(size_t)bb*2432 + i];
        h1[row*HS + f] = ihs[(size_t)(BATCH + bb)*2432 + i];
    }
    for (int i = tid; i < MR; i += 256) xprev[i] = 0.f;
    for (int i = lane; i < 32*UTS; i += 64) UtW[i] = 0;   // zero incl. k-pad cols

    // T' fragments (constant for whole kernel)
    bf16x8 tp[2][2];
    {
        const int r16 = lane & 15, quad = lane >> 4;
        #pragma unroll
        for (int mt2 = 0; mt2 < 2; ++mt2)
            #pragma unroll
            for (int kk = 0; kk < 2; ++kk)
                tp[mt2][kk] = *(const bf16x8*)&Tg[(mt2*16 + r16)*64 + kk*32 + quad*8];
    }
    const float wp0 = Wp[lane], wp1 = Wp[64 + lane], bpv = bp[0];
    __syncthreads();

    for (int t = 0; t < SEQ; ++t) {
        // ---- layer 0: sA = [xprev | h0 | 0-pad]  (K = 160) ----
        for (int idx = tid; idx < MR*160; idx += 256) {
            int row = idx/160, c = idx - row*160;
            float v = (c == 0) ? xprev[row]
                    : (c <= HH ? h0[row*HS + (c-1)] : 0.f);
            sA[row*SAS + c] = f2bf(v);
        }
        __syncthreads();
        gconv_phase<5,256,true ,1>(BTg0, bg0, h0, sA, ub, UtW, tp, lane, w);
        __syncthreads();   // r written into sA by all waves
        gconv_phase<5,128,false,1>(BTc0, bc0, h0, sA, ub, UtW, tp, lane, w);
        __syncthreads();   // h0 updated

        // ---- layer 1: sA = [h0 | h1]  (K = 256) ----
        for (int idx = tid; idx < MR*256; idx += 256) {
            int row = idx >> 8, c = idx & 255;
            float v = (c < HH) ? h0[row*HS + c] : h1[row*HS + (c-HH)];
            sA[row*SAS + c] = f2bf(v);
        }
        __syncthreads();
        gconv_phase<8,256,true ,HH>(BTg1, bg1, h1, sA, ub, UtW, tp, lane, w);
        __syncthreads();
        gconv_phase<8,128,false,HH>(BTc1, bc1, h1, sA, ub, UtW, tp, lane, w);
        __syncthreads();   // h1 updated

        // ---- projection: out[t, bb+b, n] ; wave w handles batch b=w ----
        {
            int b = w;
            for (int n = 0; n < NN; ++n) {
                int row = b*NN + n;
                float s = h1[row*HS + lane]*wp0 + h1[row*HS + 64 + lane]*wp1;
                #pragma unroll
                for (int off = 32; off; off >>= 1) s += __shfl_down(s, off, 64);
                if (lane == 0) {
                    float v = s + bpv;
                    out[((size_t)t*BATCH + bb + b)*NN + n] = v;
                    xprev[row] = v;
                }
            }
        }
        __syncthreads();
    }
}

// ---------------------------------------------------------------------------
extern "C" void kernel_launch(void* const* d_in, const int* in_sizes, int n_in,
                              void* d_out, int out_size, void* d_ws, size_t ws_size,
                              hipStream_t stream) {
    const float* ihs = (const float*)d_in[1];
    const float* S   = (const float*)d_in[2];
    const float* Wg0 = (const float*)d_in[3];   // (387,256)  F=129
    const float* bg0 = (const float*)d_in[4];
    const float* Wc0 = (const float*)d_in[5];   // (387,128)
    const float* bc0 = (const float*)d_in[6];
    const float* Wg1 = (const float*)d_in[7];   // (768,256)  F=256
    const float* bg1 = (const float*)d_in[8];
    const float* Wc1 = (const float*)d_in[9];   // (768,128)
    const float* bc1 = (const float*)d_in[10];
    const float* Wp  = (const float*)d_in[11];  // (128,1)
    const float* bp  = (const float*)d_in[12];
    float* out = (float*)d_out;

    // workspace (ushort elems): T' + 4 reordered weight blocks
    unsigned short* ws = (unsigned short*)d_ws;
    unsigned short* Tg   = ws;               // 2048
    unsigned short* BTg0 = ws + 4096;        // 3*256*160 = 122880
    unsigned short* BTc0 = BTg0 + 122880;    // 3*128*160 = 61440
    unsigned short* BTg1 = BTc0 + 61440;     // 3*256*256 = 196608
    unsigned short* BTc1 = BTg1 + 196608;    // 3*128*256 = 98304

    tprime_kernel<<<1, 256, 0, stream>>>(S, Tg);
    wconv_kernel<<<(3*256*160+255)/256, 256, 0, stream>>>(Wg0, BTg0, 129, 256, 160);
    wconv_kernel<<<(3*128*160+255)/256, 256, 0, stream>>>(Wc0, BTc0, 129, 128, 160);
    wconv_kernel<<<(3*256*256+255)/256, 256, 0, stream>>>(Wg1, BTg1, 256, 256, 256);
    wconv_kernel<<<(3*128*256+255)/256, 256, 0, stream>>>(Wc1, BTc1, 256, 128, 256);

    hipFuncSetAttribute((const void*)dcgru_persistent,
                        hipFuncAttributeMaxDynamicSharedMemorySize, LDS_BYTES);

    dcgru_persistent<<<BATCH/NB, 256, LDS_BYTES, stream>>>(
        ihs, BTg0, bg0, BTc0, bc0, BTg1, bg1, BTc1, bc1, Wp, bp, Tg, out);
}